// Round 1
// baseline (41.905 us; speedup 1.0000x reference)
//
#include <hip/hip_runtime.h>

// Problem constants (fixed by the reference file): B=8, N=4096.
#define NN 4096
#define BB 8

// One block per node j. 256 threads cooperatively compute, for all 8 batches,
//   prod_b = Prod_k (1 - ISNet[j,k] * S[b,j] * I[b,k] * p01)   in f64
// then reduce (multiply) across the block, and threads 0..7 finish the 4x4
// mixing + cumulative-threshold sampling for (b, n=j).
__global__ __launch_bounds__(256) void epi_kernel(
    const float* __restrict__ state,    // [B,4,N]
    const float* __restrict__ ISNet,    // [N,N]
    const float* __restrict__ psMatrix, // [4,4]
    const float* __restrict__ U,        // [N]
    float* __restrict__ out)            // [B,4,N]
{
    const int j   = blockIdx.x;
    const int tid = threadIdx.x;

    const double p01 = (double)psMatrix[0 * 4 + 1];  // psM[0,1] == psMatrix[0,1]

    double c[BB];     // S[b,j] * p01
    double prod[BB];
    #pragma unroll
    for (int b = 0; b < BB; ++b) {
        c[b]    = (double)state[(size_t)b * 4 * NN + 0 * NN + j] * p01;
        prod[b] = 1.0;
    }

    const float* __restrict__ wrow  = ISNet + (size_t)j * NN;
    const float* __restrict__ Ibase = state + 2 * NN;  // state[b][2][k] at Ibase + b*4*NN + k

    for (int k = tid; k < NN; k += 256) {
        const double w = (double)wrow[k];
        double Iv[BB];
        #pragma unroll
        for (int b = 0; b < BB; ++b)
            Iv[b] = (double)Ibase[(size_t)b * 4 * NN + k];
        #pragma unroll
        for (int b = 0; b < BB; ++b) {
            const double cw = c[b] * w;
            prod[b] *= fma(-cw, Iv[b], 1.0);   // (1 - w*S*I*p01), near-exact in f64
        }
    }

    // Multiply-reduce across the 64-lane wave.
    #pragma unroll
    for (int off = 32; off > 0; off >>= 1) {
        #pragma unroll
        for (int b = 0; b < BB; ++b)
            prod[b] *= __shfl_down(prod[b], off, 64);
    }

    // Cross-wave reduce via LDS (4 waves).
    __shared__ double red[4][BB];
    const int wave = tid >> 6, lane = tid & 63;
    if (lane == 0) {
        #pragma unroll
        for (int b = 0; b < BB; ++b) red[wave][b] = prod[b];
    }
    __syncthreads();

    if (tid < BB) {
        const int b = tid;
        const double tot = red[0][b] * red[1][b] * red[2][b] * red[3][b];
        const double ps1 = 1.0 - tot;

        // expand_psMatrix in f64
        double pm[4][4];
        #pragma unroll
        for (int r = 0; r < 4; ++r) {
            double s = 0.0;
            #pragma unroll
            for (int q = 0; q < 4; ++q) {
                pm[r][q] = (double)psMatrix[r * 4 + q];
                s += pm[r][q];
            }
            pm[r][r] += (1.0 - s);  // add stay probability on the diagonal
        }

        double st[4];
        #pragma unroll
        for (int r = 0; r < 4; ++r)
            st[r] = (double)state[(size_t)b * 4 * NN + r * NN + j];

        const double S = st[0];
        const double ps10[4] = {1.0 - ps1, ps1, 0.0, 0.0};

        // new_state[i] = S*ps10[i] + sum_{r=1..3} psM[r][i] * state[r]
        double P[4];
        #pragma unroll
        for (int i = 0; i < 4; ++i) {
            double acc = S * ps10[i];
            #pragma unroll
            for (int r = 1; r < 4; ++r)
                acc += pm[r][i] * st[r];
            P[i] = acc;
        }

        // cumulative-threshold sampling, shared draw U[j]
        double u = (double)U[j];
        #pragma unroll
        for (int i = 0; i < 4; ++i) {
            u -= P[i];
            const double s = (u < 0.0) ? 1.0 : 0.0;
            out[(size_t)b * 4 * NN + i * NN + j] = (float)s;
            u += s;
        }
    }
}

extern "C" void kernel_launch(void* const* d_in, const int* in_sizes, int n_in,
                              void* d_out, int out_size, void* d_ws, size_t ws_size,
                              hipStream_t stream) {
    const float* state    = (const float*)d_in[0];  // [8,4,4096]
    const float* ISNet    = (const float*)d_in[1];  // [4096,4096]
    const float* psMatrix = (const float*)d_in[2];  // [4,4]
    const float* U        = (const float*)d_in[3];  // [4096]
    float* out            = (float*)d_out;          // [8,4,4096]

    epi_kernel<<<NN, 256, 0, stream>>>(state, ISNet, psMatrix, U, out);
}